// Round 4
// baseline (4917.657 us; speedup 1.0000x reference)
//
#include <hip/hip_runtime.h>
#include <cstdint>
#include <cstddef>

#define FEAT 256
#define HWPX 16384
#define NDIR 10000
#define NCLS 4          // classes 1..4
#define BCAP 4096       // per-class column capacity for B (n_c ~ 3277)
#define NSWO 7          // outer block-Jacobi sweeps (fixed, deterministic)
#define JTOL 4e-12f     // skip rotation if d^2 <= na*nb*JTOL
#define NBLK_FP 157     // ceil(NDIR/64)
#define NRND (NSWO*31)  // 217 rounds (16-wave ring, 32 groups of 8)

// ---- workspace layout (element offsets; 4B elements) ----
static const size_t OFF_FEATT = 0;                                // 16384*256 f32
static const size_t OFF_IDX   = OFF_FEATT + (size_t)HWPX*FEAT;    // 4*16384 int
static const size_t OFF_CNT   = OFF_IDX + (size_t)NCLS*HWPX;      // 4 int (+pad)
static const size_t OFF_MIU   = OFF_CNT + 64;                     // 4*256 f32
static const size_t OFF_MIUP  = OFF_MIU + (size_t)NCLS*FEAT;      // 32*4*256 f32 partials
static const size_t OFF_G     = OFF_MIUP + (size_t)32*NCLS*FEAT;  // 4*65536 f32
static const size_t OFF_ETS   = OFF_G + (size_t)NCLS*FEAT*FEAT;   // 4*65536 f32
static const size_t OFF_EVAL  = OFF_ETS + (size_t)NCLS*FEAT*FEAT; // 4*256 f32
static const size_t OFF_LPART = OFF_EVAL + (size_t)NCLS*FEAT;     // 4*160*2 f32 per-block partials
static const size_t OFF_B     = OFF_LPART + (size_t)NCLS*160*2;   // 4*256*BCAP f32
static const size_t OFF_XCH   = OFF_B + (size_t)NCLS*FEAT*BCAP;   // 4*131072 f32 region per class
// per-class sub-layout inside XCH (stride 131072 floats = 512 KB):
//   QIN_w  at w*4096       (w=0..15): 2 slots x 2048 floats (Q arriving at wave w)
//   PIN_w  at 65536+w*4096 (w=1..14): 2 slots x 2048 floats (P arriving at wave w)
//   csqg   at 65536 + 0    (PIN_0 hole, 256 f32: exact column norms)
//   flags  at 65536 + 1024 (PIN_0 hole, ints): dP[16] crP[16] dQ[16] crQ[16] bar
// total unchanged (~39 MB)

#define XCH_STRIDE  ((size_t)131072)
#define XCH_PIN_OFF 65536
#define XCH_FLG_OFF (65536 + 1024)

// 64-lane sum, deterministic fixed order, result uniform.
__device__ __forceinline__ float wsum64(float v){
  int x;
  x = __builtin_amdgcn_update_dpp(0, __float_as_int(v), 0x121, 0xF, 0xF, false); v += __int_as_float(x); // row_ror:1
  x = __builtin_amdgcn_update_dpp(0, __float_as_int(v), 0x122, 0xF, 0xF, false); v += __int_as_float(x); // row_ror:2
  x = __builtin_amdgcn_update_dpp(0, __float_as_int(v), 0x124, 0xF, 0xF, false); v += __int_as_float(x); // row_ror:4
  x = __builtin_amdgcn_update_dpp(0, __float_as_int(v), 0x128, 0xF, 0xF, false); v += __int_as_float(x); // row_ror:8
  float a = __int_as_float(__builtin_amdgcn_readlane(__float_as_int(v), 0));
  float b = __int_as_float(__builtin_amdgcn_readlane(__float_as_int(v), 16));
  float c = __int_as_float(__builtin_amdgcn_readlane(__float_as_int(v), 32));
  float d = __int_as_float(__builtin_amdgcn_readlane(__float_as_int(v), 48));
  return (a + b) + (c + d);
}

// AGENT-scope relaxed atomics: sc1 on the access itself (L2-bypass, LLC-coherent
// cross-XCD path). No wbl2/inv fences, no HBM write-through (vs system scope).
__device__ __forceinline__ void sysst(float* p, float v){
  __hip_atomic_store(p, v, __ATOMIC_RELAXED, __HIP_MEMORY_SCOPE_AGENT);
}
__device__ __forceinline__ float sysld(const float* p){
  return __hip_atomic_load(p, __ATOMIC_RELAXED, __HIP_MEMORY_SCOPE_AGENT);
}
__device__ __forceinline__ void syssti(int* p, int v){
  __hip_atomic_store(p, v, __ATOMIC_RELAXED, __HIP_MEMORY_SCOPE_AGENT);
}
__device__ __forceinline__ int sysldi(const int* p){
  return __hip_atomic_load(p, __ATOMIC_RELAXED, __HIP_MEMORY_SCOPE_AGENT);
}
// whole-wave spin until *f >= val
__device__ __forceinline__ void waitflag(int* f, int val){
  while (sysldi(f) < val) __builtin_amdgcn_s_sleep(1);
  asm volatile("" ::: "memory");
}

// ---------------- transpose feat (256 x 16384) -> featT (16384 x 256) ----------------
__global__ __launch_bounds__(256) void k_transpose(const float* __restrict__ feat, float* __restrict__ ws){
  __shared__ float tile[32][33];
  float* featT = ws + OFF_FEATT;
  int j0 = blockIdx.x*32, f0 = blockIdx.y*32;
  int tx = threadIdx.x, ty = threadIdx.y; // (32, 8)
  #pragma unroll
  for (int r=0;r<4;r++){
    int f = f0 + ty + r*8;
    tile[ty+r*8][tx] = feat[(size_t)f*HWPX + j0 + tx];
  }
  __syncthreads();
  #pragma unroll
  for (int r=0;r<4;r++){
    int j = j0 + ty + r*8;
    featT[(size_t)j*FEAT + f0 + tx] = tile[tx][ty+r*8];
  }
}

// ---------------- build compacted per-class index lists + counts (+ zero jacobi flags) ----------------
__global__ __launch_bounds__(256) void k_index(const int* __restrict__ lab, float* ws){
  __shared__ int sc[256];
  int* idx = (int*)(ws + OFF_IDX);
  int* cnt = (int*)(ws + OFF_CNT);
  int t = threadIdx.x;
  // zero k_jacobi sync flags every launch (graph replay safe; stream-ordered before k_jacobi)
  if (t < 96){
    #pragma unroll
    for (int cc=0; cc<NCLS; cc++){
      int* fb = (int*)(ws + OFF_XCH + (size_t)cc*XCH_STRIDE + XCH_FLG_OFF);
      fb[t] = 0;
    }
  }
  int base = t*64;
  for (int c=1;c<=NCLS;c++){
    __syncthreads();
    int m = 0;
    for (int k=0;k<64;k++) m += (lab[base+k]==c) ? 1 : 0;
    sc[t] = m;
    __syncthreads();
    for (int off=1; off<256; off<<=1){
      int v = (t>=off)? sc[t-off] : 0;
      __syncthreads();
      sc[t] += v;
      __syncthreads();
    }
    int pos = sc[t] - m;
    if (t==255) cnt[c-1] = sc[255];
    int* ic = idx + (size_t)(c-1)*HWPX;
    for (int k=0;k<64;k++){
      if (lab[base+k]==c) ic[pos++] = base+k;
    }
  }
}

// ---------------- per-class feature-sum partials (deterministic, no atomics) ----------------
__global__ __launch_bounds__(256) void k_miu_part(const int* __restrict__ lab, float* ws){
  const float* featT = ws + OFF_FEATT;
  float* part = ws + OFF_MIUP;
  int f = threadIdx.x;
  int b = blockIdx.x;
  int j0 = b*512;
  float a0=0.f,a1=0.f,a2=0.f,a3=0.f;
  for (int j=j0;j<j0+512;j++){
    float v = featT[(size_t)j*FEAT + f];
    int c = lab[j];
    a0 += (c==1)? v : 0.f;
    a1 += (c==2)? v : 0.f;
    a2 += (c==3)? v : 0.f;
    a3 += (c==4)? v : 0.f;
  }
  float* pb = part + (size_t)b*NCLS*FEAT;
  pb[0*FEAT+f] = a0;
  pb[1*FEAT+f] = a1;
  pb[2*FEAT+f] = a2;
  pb[3*FEAT+f] = a3;
}

__global__ __launch_bounds__(1024) void k_miu_fin(float* ws){
  int t = threadIdx.x;            // 0..1023 = c*FEAT+f
  int c = t / FEAT;
  const float* part = ws + OFF_MIUP;
  float s = 0.f;
  for (int b=0;b<32;b++) s += part[(size_t)b*NCLS*FEAT + t];   // fixed order
  int n = ((int*)(ws+OFF_CNT))[c];
  float nf = fmaxf((float)n, 1.f);
  ws[OFF_MIU + t] = s / nf;
}

// ---------------- cov per class (64x64 tiles): G = m2mat/n - miu miu^T + eps I ----------------
__global__ __launch_bounds__(256) void k_cov(float* ws){
  __shared__ float Xa[32][68];
  __shared__ float Xb[32][68];
  const float* featT = ws + OFF_FEATT;
  int c = blockIdx.y;
  const int* idx = (const int*)(ws + OFF_IDX) + (size_t)c*HWPX;
  int n = ((int*)(ws+OFF_CNT))[c];
  float nf = fmaxf((float)n,1.f);
  const float* miu = ws + OFF_MIU + (size_t)c*FEAT;
  float* G = ws + OFF_G + (size_t)c*FEAT*FEAT;
  int fb = (blockIdx.x & 3)*64, gb = (blockIdx.x >> 2)*64;
  int t = threadIdx.x;
  int ti = t & 15, tj = t >> 4;
  float acc[4][4] = {};
  int jr = t >> 3;         // 0..31
  int s8 = (t & 7) * 8;    // 0..56
  int nch = (n + 31)/32;
  for (int ch=0; ch<nch; ch++){
    int jg = ch*32 + jr;
    __syncthreads();
    if (jg < n){
      int jx = idx[jg];
      const float* row = featT + (size_t)jx*FEAT;
      #pragma unroll
      for (int k=0;k<8;k++){ Xa[jr][s8+k] = row[fb+s8+k]; Xb[jr][s8+k] = row[gb+s8+k]; }
    } else {
      #pragma unroll
      for (int k=0;k<8;k++){ Xa[jr][s8+k] = 0.f; Xb[jr][s8+k] = 0.f; }
    }
    __syncthreads();
    for (int jj=0;jj<32;jj++){
      float4 av = *(const float4*)&Xa[jj][ti*4];
      float4 bv = *(const float4*)&Xb[jj][tj*4];
      float aa[4] = {av.x,av.y,av.z,av.w};
      float bb[4] = {bv.x,bv.y,bv.z,bv.w};
      #pragma unroll
      for (int ii=0; ii<4; ii++)
        #pragma unroll
        for (int j2=0; j2<4; j2++)
          acc[ii][j2] += aa[ii]*bb[j2];
    }
  }
  float eps = fminf(fmaxf(1e-5f/nf, 1e-8f), 1e-5f);
  #pragma unroll
  for (int ii=0; ii<4; ii++){
    #pragma unroll
    for (int j2=0; j2<4; j2++){
      int f = fb + ti*4 + ii, g = gb + tj*4 + j2;
      float v = acc[ii][j2]/nf - miu[f]*miu[g] + ((f==g)? eps : 0.f);
      G[(size_t)g*FEAT + f] = v;   // column-major, col g
    }
  }
}

// ---------------- one-sided BLOCK Jacobi, systolic 16-wave ring, 8-col groups ----------------
// R1's exact 16-wave / 32-groups-of-8 tournament (217 rounds, convergence-verified)
// run on R3's proven credit-mailbox transit (bit-exact protocol), with mailboxes at
// AGENT scope (sc1: LLC-coherent cross-XCD, no HBM write-through, no wbl2/inv).
// 1 wave = 1 WG; all 16 columns live in registers; rotations are pure VALU.
// Protocol per round R (publish-before-wait => deadlock-free by induction):
//   1. credit waits  2. data stores (slot (R+1)&1)  3. vmcnt(0)  4. d-flag:=R+1
//   5. tail reg-move 6. wait d>=R+1  7. loads  8. vmcnt(0)  9. credit:=R+1
__global__ __launch_bounds__(64) void k_jacobi(float* ws){
  int c = blockIdx.y;
  int w = blockIdx.x;                 // ring wave 0..15
  float* G    = ws + OFF_G + (size_t)c*FEAT*FEAT;
  float* XC   = ws + OFF_XCH + (size_t)c*XCH_STRIDE;
  float* QIN  = XC;                   // w*4096 (+ sl*2048)
  float* PIN  = XC + XCH_PIN_OFF;     // w*4096 (+ sl*2048), w=1..14
  float* csqg = XC + XCH_PIN_OFF;     // PIN_0 hole [0..255]
  int*   flg  = (int*)(XC + XCH_FLG_OFF);
  int* dP = flg;       int* crP = flg+16;
  int* dQ = flg+32;    int* crQ = flg+48;
  int* bar = flg+64;
  int lane = threadIdx.x;
  int lane4 = lane*4;

#define FORJ8L(M) M(0) M(1) M(2) M(3) M(4) M(5) M(6) M(7)
#define FORJ8H(M) M(8) M(9) M(10) M(11) M(12) M(13) M(14) M(15)

  // 16 resident columns: 0..7 = P (group pg), 8..15 = Q (group qg)
#define DECL(j) float C##j##x, C##j##y, C##j##z, C##j##w;
  FORJ8L(DECL) FORJ8H(DECL)
#undef DECL
  float n0,n1,n2,n3,n4,n5,n6,n7,n8,n9,n10,n11,n12,n13,n14,n15;

  int pg = (w==0)? 31 : w;        // initial (and final) group ids
  int qg = (w==0)? 0  : 31 - w;

  // initial load (plain cached loads; G flushed at kernel boundary)
#define LDP(j) { float4 v_ = *(const float4*)&G[(size_t)(pg*8+(j))*FEAT + lane4]; \
                 C##j##x=v_.x; C##j##y=v_.y; C##j##z=v_.z; C##j##w=v_.w; }
  FORJ8L(LDP)
#undef LDP
#define LDQ(j) { float4 v_ = *(const float4*)&G[(size_t)(qg*8+((j)-8))*FEAT + lane4]; \
                 C##j##x=v_.x; C##j##y=v_.y; C##j##z=v_.z; C##j##w=v_.w; }
  FORJ8H(LDQ)
#undef LDQ

#define RG(g,ax,ay,az,aw)  ax=C##g##x; ay=C##g##y; az=C##g##z; aw=C##g##w;
#define WRG(g,ax,ay,az,aw) C##g##x=ax; C##g##y=ay; C##g##z=az; C##g##w=aw;
#define NRM(j) n##j = wsum64(C##j##x*C##j##x + C##j##y*C##j##y + C##j##z*C##j##z + C##j##w*C##j##w);

  // Branchless rotation (value-identical to branchy form; verified bit-exact R3).
#define ROTG(ga,gb) { \
    float ax,ay,az,aw,bx,by,bz,bw; \
    RG(ga,ax,ay,az,aw) \
    RG(gb,bx,by,bz,bw) \
    float dp = ax*bx + ay*by + az*bz + aw*bw; \
    float d = wsum64(dp); \
    float na = n##ga, nb = n##gb; \
    bool doit = (d*d > na*nb*JTOL); \
    float tau = (nb - na) * 0.5f * __builtin_amdgcn_rcpf(d); \
    float tt = copysignf(__builtin_amdgcn_rcpf(fabsf(tau) + __builtin_amdgcn_sqrtf(1.f + tau*tau)), tau); \
    float cc = __builtin_amdgcn_rsqf(1.f + tt*tt); \
    float sn = tt*cc; \
    cc = doit ? cc : 1.f; \
    sn = doit ? sn : 0.f; \
    float x_; \
    x_ = ax; ax = cc*x_ - sn*bx; bx = sn*x_ + cc*bx; \
    x_ = ay; ay = cc*x_ - sn*by; by = sn*x_ + cc*by; \
    x_ = az; az = cc*x_ - sn*bz; bz = sn*x_ + cc*bz; \
    x_ = aw; aw = cc*x_ - sn*bw; bw = sn*x_ + cc*bw; \
    float cc2 = cc*cc, sn2 = sn*sn, csd = 2.f*cc*sn*d; \
    n##ga = cc2*na - csd + sn2*nb; \
    n##gb = sn2*na + csd + cc2*nb; \
    WRG(ga,ax,ay,az,aw) \
    WRG(gb,bx,by,bz,bw) \
  }

  // mailbox column store/load (agent-relaxed dword atomics; coalesced lane4 layout)
#define STC(d_, j) { float* p_ = (d_) + ((j)&7)*256 + lane4; \
    sysst(p_+0, C##j##x); sysst(p_+1, C##j##y); sysst(p_+2, C##j##z); sysst(p_+3, C##j##w); }
#define LDC(s_, j) { const float* p_ = (s_) + ((j)&7)*256 + lane4; \
    C##j##x=sysld(p_+0); C##j##y=sysld(p_+1); C##j##z=sysld(p_+2); C##j##w=sysld(p_+3); }

  bool hasP = (w>=1 && w<=14);    // receives P mailbox
  float* pubPdst = (w==1)? QIN : PIN + (size_t)(w-1)*4096;   // w>=1
  int*   pubPd   = (w==1)? (dQ+0) : (dP+(w-1));
  int*   pubPcr  = (w==1)? (crQ+0) : (crP+(w-1));

#pragma clang loop unroll(disable)
  for (int R=0; R<NRND; R++){
    // exact column norms (refreshed each round; uniform across lanes)
    NRM(0) NRM(1) NRM(2) NRM(3) NRM(4) NRM(5) NRM(6) NRM(7)
    NRM(8) NRM(9) NRM(10) NRM(11) NRM(12) NRM(13) NRM(14) NRM(15)
    // ---- cross pairs: 8 micro-rounds of 8 disjoint (i, 8+((i+s)&7)) ----
    ROTG(0,8)  ROTG(1,9)  ROTG(2,10) ROTG(3,11) ROTG(4,12) ROTG(5,13) ROTG(6,14) ROTG(7,15)
    ROTG(0,9)  ROTG(1,10) ROTG(2,11) ROTG(3,12) ROTG(4,13) ROTG(5,14) ROTG(6,15) ROTG(7,8)
    ROTG(0,10) ROTG(1,11) ROTG(2,12) ROTG(3,13) ROTG(4,14) ROTG(5,15) ROTG(6,8)  ROTG(7,9)
    ROTG(0,11) ROTG(1,12) ROTG(2,13) ROTG(3,14) ROTG(4,15) ROTG(5,8)  ROTG(6,9)  ROTG(7,10)
    ROTG(0,12) ROTG(1,13) ROTG(2,14) ROTG(3,15) ROTG(4,8)  ROTG(5,9)  ROTG(6,10) ROTG(7,11)
    ROTG(0,13) ROTG(1,14) ROTG(2,15) ROTG(3,8)  ROTG(4,9)  ROTG(5,10) ROTG(6,11) ROTG(7,12)
    ROTG(0,14) ROTG(1,15) ROTG(2,8)  ROTG(3,9)  ROTG(4,10) ROTG(5,11) ROTG(6,12) ROTG(7,13)
    ROTG(0,15) ROTG(1,8)  ROTG(2,9)  ROTG(3,10) ROTG(4,11) ROTG(5,12) ROTG(6,13) ROTG(7,14)
    // ---- intra-group pairs every 4th round (7-round circle per group) ----
    if ((R & 3) == 3){
      ROTG(7,0) ROTG(1,6) ROTG(2,5) ROTG(3,4)  ROTG(15,8)  ROTG(9,14)  ROTG(10,13) ROTG(11,12)
      ROTG(7,1) ROTG(2,0) ROTG(3,6) ROTG(4,5)  ROTG(15,9)  ROTG(10,8)  ROTG(11,14) ROTG(12,13)
      ROTG(7,2) ROTG(3,1) ROTG(4,0) ROTG(5,6)  ROTG(15,10) ROTG(11,9)  ROTG(12,8)  ROTG(13,14)
      ROTG(7,3) ROTG(4,2) ROTG(5,1) ROTG(6,0)  ROTG(15,11) ROTG(12,10) ROTG(13,9)  ROTG(14,8)
      ROTG(7,4) ROTG(5,3) ROTG(6,2) ROTG(0,1)  ROTG(15,12) ROTG(13,11) ROTG(14,10) ROTG(8,9)
      ROTG(7,5) ROTG(6,4) ROTG(0,3) ROTG(1,2)  ROTG(15,13) ROTG(14,12) ROTG(8,11)  ROTG(9,10)
      ROTG(7,6) ROTG(0,5) ROTG(1,4) ROTG(2,3)  ROTG(15,14) ROTG(8,13)  ROTG(9,12)  ROTG(10,11)
    }

    int sl = (R+1) & 1;           // slot parity for data-for-round R+1
    // 1. credit waits (slot free: consumer consumed round R-1)
    if (w >= 1) waitflag(pubPcr, R-1);
    if (w <= 14) waitflag(crQ+(w+1), R-1);
    // 2. publish data
    if (w >= 1){
      float* db = pubPdst + sl*2048;
      STC(db,0) STC(db,1) STC(db,2) STC(db,3) STC(db,4) STC(db,5) STC(db,6) STC(db,7)
    }
    if (w <= 14){
      float* db = QIN + (size_t)(w+1)*4096 + sl*2048;
      STC(db,8) STC(db,9) STC(db,10) STC(db,11) STC(db,12) STC(db,13) STC(db,14) STC(db,15)
    }
    // 3. data stores complete before flags become visible
    asm volatile("s_waitcnt vmcnt(0)" ::: "memory");
    // 4. publish data flags
    if (w >= 1) syssti(pubPd, R+1);
    if (w <= 14) syssti(dQ+(w+1), R+1);
    // 5. ring tail: newP_15 = own oldQ (register moves; P stores already completed)
    if (w == 15){
      C0x=C8x;  C0y=C8y;  C0z=C8z;  C0w=C8w;
      C1x=C9x;  C1y=C9y;  C1z=C9z;  C1w=C9w;
      C2x=C10x; C2y=C10y; C2z=C10z; C2w=C10w;
      C3x=C11x; C3y=C11y; C3z=C11z; C3w=C11w;
      C4x=C12x; C4y=C12y; C4z=C12z; C4w=C12w;
      C5x=C13x; C5y=C13y; C5z=C13z; C5w=C13w;
      C6x=C14x; C6y=C14y; C6z=C14z; C6w=C14w;
      C7x=C15x; C7y=C15y; C7z=C15z; C7w=C15w;
    }
    // 6. wait for round R+1 inputs
    if (hasP) waitflag(dP+w, R+1);
    waitflag(dQ+w, R+1);
    // 7. receive loads
    if (hasP){
      const float* sb = PIN + (size_t)w*4096 + sl*2048;
      LDC(sb,0) LDC(sb,1) LDC(sb,2) LDC(sb,3) LDC(sb,4) LDC(sb,5) LDC(sb,6) LDC(sb,7)
    }
    {
      const float* sb = QIN + (size_t)w*4096 + sl*2048;
      LDC(sb,8) LDC(sb,9) LDC(sb,10) LDC(sb,11) LDC(sb,12) LDC(sb,13) LDC(sb,14) LDC(sb,15)
    }
    // 8. loads complete before credits release the slots
    asm volatile("s_waitcnt vmcnt(0)" ::: "memory");
    // 9. credits out
    if (hasP) syssti(crP+w, R+1);
    syssti(crQ+w, R+1);
  }

  // ---- extraction: exact norms -> csqg, class barrier, per-wave rank, normalized rows ----
  NRM(0) NRM(1) NRM(2) NRM(3) NRM(4) NRM(5) NRM(6) NRM(7)
  NRM(8) NRM(9) NRM(10) NRM(11) NRM(12) NRM(13) NRM(14) NRM(15)
  int pcol = pg*8, qcol = qg*8;
#define WCSP(j) if (lane == (j)) sysst(&csqg[pcol+(j)], n##j);
#define WCSQ(j) if (lane == (j)) sysst(&csqg[qcol+(j)-8], n##j);
  WCSP(0) WCSP(1) WCSP(2) WCSP(3) WCSP(4) WCSP(5) WCSP(6) WCSP(7)
  WCSQ(8) WCSQ(9) WCSQ(10) WCSQ(11) WCSQ(12) WCSQ(13) WCSQ(14) WCSQ(15)
#undef WCSP
#undef WCSQ
  asm volatile("s_waitcnt vmcnt(0)" ::: "memory");
  if (lane == 0) __hip_atomic_fetch_add(bar, 1, __ATOMIC_RELAXED, __HIP_MEMORY_SCOPE_AGENT);
  while (sysldi(bar) < 16) __builtin_amdgcn_s_sleep(1);
  asm volatile("" ::: "memory");
  // all 256 norms; each lane holds 4
  float q0 = sysld(&csqg[lane4+0]);
  float q1 = sysld(&csqg[lane4+1]);
  float q2 = sysld(&csqg[lane4+2]);
  float q3 = sysld(&csqg[lane4+3]);
  int u0 = lane4, u1 = lane4+1, u2 = lane4+2, u3 = lane4+3;
  float* evals = ws + OFF_EVAL + (size_t)c*FEAT;
  float* Et = ws + OFF_ETS + (size_t)c*FEAT*FEAT;
  // rank(col X, norm nv) = #{u : csq[u] > nv || (== && u < X)}  (same comparator)
#define RANKWR(j, X) { \
    float nv = n##j; \
    float cnt = (((q0>nv)||(q0==nv&&u0<(X)))?1.f:0.f) + (((q1>nv)||(q1==nv&&u1<(X)))?1.f:0.f) \
              + (((q2>nv)||(q2==nv&&u2<(X)))?1.f:0.f) + (((q3>nv)||(q3==nv&&u3<(X)))?1.f:0.f); \
    int rk = (int)wsum64(cnt); \
    if (lane == 0) evals[rk] = sqrtf(nv); \
    float iv = 1.f / sqrtf(nv); \
    float4 v_; v_.x=C##j##x*iv; v_.y=C##j##y*iv; v_.z=C##j##z*iv; v_.w=C##j##w*iv; \
    *(float4*)&Et[(size_t)rk*FEAT + lane4] = v_; \
  }
  RANKWR(0,  pcol+0) RANKWR(1,  pcol+1) RANKWR(2,  pcol+2) RANKWR(3,  pcol+3)
  RANKWR(4,  pcol+4) RANKWR(5,  pcol+5) RANKWR(6,  pcol+6) RANKWR(7,  pcol+7)
  RANKWR(8,  qcol+0) RANKWR(9,  qcol+1) RANKWR(10, qcol+2) RANKWR(11, qcol+3)
  RANKWR(12, qcol+4) RANKWR(13, qcol+5) RANKWR(14, qcol+6) RANKWR(15, qcol+7)
#undef RANKWR
#undef ROTG
#undef NRM
#undef RG
#undef WRG
#undef STC
#undef LDC
#undef FORJ8L
#undef FORJ8H
}

// ---------------- B[c] = EtS (256x256, sorted) @ centered_gathered (256 x n_c) ----------------
__global__ __launch_bounds__(256) void k_bmat(float* ws){
  __shared__ float Ae[256][68];   // [f][k-local]
  __shared__ float Bc[256][68];   // [f][j-local]
  int c = blockIdx.z;
  int n = ((int*)(ws+OFF_CNT))[c];
  int j0 = blockIdx.x*64;
  if (j0 >= n) return;            // block-uniform
  int kb = blockIdx.y*64;
  const float* featT = ws + OFF_FEATT;
  const int* idx = (const int*)(ws + OFF_IDX) + (size_t)c*HWPX;
  const float* miu = ws + OFF_MIU + (size_t)c*FEAT;
  const float* Ets = ws + OFF_ETS + (size_t)c*FEAT*FEAT;
  float* Bg = ws + OFF_B + (size_t)c*FEAT*BCAP;
  int t = threadIdx.x;
  int l4 = t >> 2, sgf = (t & 3)*64;
  // stage Ae
  {
    const float* Erow = Ets + (size_t)(kb+l4)*FEAT + sgf;
    for (int f=0; f<64; f+=4){
      float4 v = *(const float4*)&Erow[f];
      Ae[sgf+f+0][l4] = v.x; Ae[sgf+f+1][l4] = v.y;
      Ae[sgf+f+2][l4] = v.z; Ae[sgf+f+3][l4] = v.w;
    }
  }
  // stage Bc (centered gathered columns)
  {
    int jg = j0 + l4;
    if (jg < n){
      const float* Frow = featT + (size_t)idx[jg]*FEAT + sgf;
      const float* mp = miu + sgf;
      for (int f=0; f<64; f+=4){
        float4 v = *(const float4*)&Frow[f];
        Bc[sgf+f+0][l4] = v.x - mp[f+0];
        Bc[sgf+f+1][l4] = v.y - mp[f+1];
        Bc[sgf+f+2][l4] = v.z - mp[f+2];
        Bc[sgf+f+3][l4] = v.w - mp[f+3];
      }
    } else {
      for (int f=0; f<64; f++) Bc[sgf+f][l4] = 0.f;
    }
  }
  __syncthreads();
  int ti = t & 15, tj = t >> 4;   // ti: k-sub, tj: j-sub
  float acc[4][4] = {};
  for (int f=0; f<FEAT; f+=4){
    #pragma unroll
    for (int ff=0; ff<4; ff++){
      float4 av = *(const float4*)&Ae[f+ff][ti*4];
      float4 bv = *(const float4*)&Bc[f+ff][tj*4];
      float aa[4] = {av.x,av.y,av.z,av.w};
      float bb[4] = {bv.x,bv.y,bv.z,bv.w};
      #pragma unroll
      for (int kk=0;kk<4;kk++)
        #pragma unroll
        for (int jj=0;jj<4;jj++)
          acc[kk][jj] += aa[kk]*bb[jj];
    }
  }
  #pragma unroll
  for (int kk=0; kk<4; kk++){
    float4 o; o.x=acc[kk][0]; o.y=acc[kk][1]; o.z=acc[kk][2]; o.w=acc[kk][3];
    *(float4*)&Bg[(size_t)(kb + ti*4 + kk)*BCAP + j0 + tj*4] = o;
  }
}

// ---------------- fp GEMM (pm @ B) with fused m2/m4 + per-block loss partials ----------------
__global__ __launch_bounds__(256) void k_fp(const float* __restrict__ pm, float* ws){
  __shared__ float As[256][68];   // [k][i-local]  (pm tile, transposed)
  __shared__ float Bs[256][68];   // [k][j-local]
  __shared__ float ev[256];
  __shared__ float red[64][17];
  __shared__ float m2s[64];
  __shared__ float m4s[64];
  int c = blockIdx.y;
  int i0 = blockIdx.x*64;
  int n = ((int*)(ws+OFF_CNT))[c];
  float nf = fmaxf((float)n, 1.f);
  const float* evals = ws + OFF_EVAL + (size_t)c*FEAT;
  const float* Bg = ws + OFF_B + (size_t)c*FEAT*BCAP;
  int t = threadIdx.x;
  int l4 = t >> 2;
  // stage As
  {
    int sgf = (t & 3)*64;
    int gi = i0 + l4;
    if (gi < NDIR){
      const float* row = pm + (size_t)gi*FEAT + sgf;
      for (int f=0; f<64; f+=4){
        float4 v = *(const float4*)&row[f];
        As[sgf+f+0][l4] = v.x; As[sgf+f+1][l4] = v.y;
        As[sgf+f+2][l4] = v.z; As[sgf+f+3][l4] = v.w;
      }
    } else {
      for (int f=0; f<64; f++) As[sgf+f][l4] = 0.f;
    }
  }
  if (t < 256) ev[t] = evals[t];
  int ti = t & 15, tj = t >> 4;
  float s2[4] = {0.f,0.f,0.f,0.f};
  float s4[4] = {0.f,0.f,0.f,0.f};
  int nch = (n + 63)/64;
  int sgj = (t & 3)*16;
  for (int ch=0; ch<nch; ch++){
    int j0 = ch*64;
    __syncthreads();
    for (int g=0; g<4; g++){
      int r = l4 + 64*g;
      const float* Brow = Bg + (size_t)r*BCAP + j0 + sgj;
      #pragma unroll
      for (int e=0; e<16; e+=4){
        int j = j0 + sgj + e;
        float4 v;
        if (j + 3 < n) v = *(const float4*)&Brow[e];
        else {
          v.x = (j+0<n)? Brow[e+0] : 0.f;
          v.y = (j+1<n)? Brow[e+1] : 0.f;
          v.z = (j+2<n)? Brow[e+2] : 0.f;
          v.w = (j+3<n)? Brow[e+3] : 0.f;
        }
        *(float4*)&Bs[r][sgj+e] = v;
      }
    }
    __syncthreads();
    float acc[4][4] = {};
    for (int k=0; k<FEAT; k+=4){
      #pragma unroll
      for (int kk=0; kk<4; kk++){
        float4 av = *(const float4*)&As[k+kk][ti*4];
        float4 bv = *(const float4*)&Bs[k+kk][tj*4];
        float aa[4] = {av.x,av.y,av.z,av.w};
        float bb[4] = {bv.x,bv.y,bv.z,bv.w};
        #pragma unroll
        for (int ii=0;ii<4;ii++)
          #pragma unroll
          for (int jj=0;jj<4;jj++)
            acc[ii][jj] += aa[ii]*bb[jj];
      }
    }
    #pragma unroll
    for (int ii=0;ii<4;ii++){
      #pragma unroll
      for (int jj=0;jj<4;jj++){
        float v = acc[ii][jj];
        float v2 = v*v;
        s2[ii] += v2;
        s4[ii] += v2*v2;
      }
    }
  }
  __syncthreads();
  #pragma unroll
  for (int ii=0;ii<4;ii++) red[ti*4+ii][tj] = s2[ii];
  __syncthreads();
  if (t < 64){
    float s = 0.f;
    for (int u=0;u<16;u++) s += red[t][u];
    m2s[t] = s;
  }
  __syncthreads();
  #pragma unroll
  for (int ii=0;ii<4;ii++) red[ti*4+ii][tj] = s4[ii];
  __syncthreads();
  if (t < 64){
    float s = 0.f;
    for (int u=0;u<16;u++) s += red[t][u];
    m4s[t] = s;
  }
  __syncthreads();
  if (t < 64){
    float stds = 0.f;
    for (int k=0;k<FEAT;k++){
      float a = As[k][t];
      stds += a*a*ev[k];
    }
    int i = i0 + t;
    float l2 = 0.f, lk = 0.f;
    if (i < NDIR){
      float m2 = m2s[t]/(nf*stds);
      float m4 = m4s[t]/(nf*stds*stds);
      float d2 = m2 - 1.f;
      l2 = d2*d2;
      float dk = m4 - 3.f*m2*m2;
      lk = dk*dk;
    }
    #pragma unroll
    for (int o=1;o<64;o<<=1){
      l2 += __shfl_xor(l2, o);
      lk += __shfl_xor(lk, o);
    }
    if (t == 0){
      float* lp = ws + OFF_LPART + ((size_t)c*160 + blockIdx.x)*2;
      lp[0] = l2;
      lp[1] = lk;
    }
  }
}

// ---------------- final scalar (deterministic fixed-order reduction) ----------------
__global__ __launch_bounds__(64) void k_final(float* ws, float* out){
  int t = threadIdx.x;   // one wave
  const int* cnt = (const int*)(ws + OFF_CNT);
  const float* lp = ws + OFF_LPART;
  float tot = 0.f, an = 0.f;
  for (int c=0;c<NCLS;c++){
    float s2 = 0.f, sk = 0.f;
    for (int b=t; b<NBLK_FP; b+=64){
      s2 += lp[((size_t)c*160 + b)*2 + 0];
      sk += lp[((size_t)c*160 + b)*2 + 1];
    }
    #pragma unroll
    for (int o=1;o<64;o<<=1){
      s2 += __shfl_xor(s2, o);
      sk += __shfl_xor(sk, o);
    }
    if (cnt[c] > 0){
      tot += s2/(float)NDIR + sk/(float)NDIR;
      an += 1.f;
    }
  }
  if (t == 0) out[0] = tot / fmaxf(an, 1.f);
}

extern "C" void kernel_launch(void* const* d_in, const int* in_sizes, int n_in,
                              void* d_out, int out_size, void* d_ws, size_t ws_size,
                              hipStream_t stream) {
  const float* feat = (const float*)d_in[0];
  const int*   lab  = (const int*)d_in[1];
  const float* pm   = (const float*)d_in[2];
  float* out = (float*)d_out;
  float* ws  = (float*)d_ws;

  hipLaunchKernelGGL(k_transpose, dim3(HWPX/32, FEAT/32), dim3(32,8), 0, stream, feat, ws);
  hipLaunchKernelGGL(k_index,     dim3(1),            dim3(256),     0, stream, lab, ws);
  hipLaunchKernelGGL(k_miu_part,  dim3(32),           dim3(256),     0, stream, lab, ws);
  hipLaunchKernelGGL(k_miu_fin,   dim3(1),            dim3(1024),    0, stream, ws);
  hipLaunchKernelGGL(k_cov,       dim3(16, NCLS),     dim3(256),     0, stream, ws);
  hipLaunchKernelGGL(k_jacobi,    dim3(16, NCLS),     dim3(64),      0, stream, ws);
  hipLaunchKernelGGL(k_bmat,      dim3(BCAP/64, 4, NCLS), dim3(256), 0, stream, ws);
  hipLaunchKernelGGL(k_fp,        dim3(NBLK_FP, NCLS), dim3(256),    0, stream, pm, ws);
  hipLaunchKernelGGL(k_final,     dim3(1),            dim3(64),      0, stream, ws, out);
}

// Round 6
// 4660.403 us; speedup vs baseline: 1.0552x; 1.0552x over previous
//
#include <hip/hip_runtime.h>
#include <cstdint>
#include <cstddef>

#define FEAT 256
#define HWPX 16384
#define NDIR 10000
#define NCLS 4          // classes 1..4
#define BCAP 4096       // per-class column capacity for B (n_c ~ 3277)
#define NSWO 7          // outer block-Jacobi sweeps (fixed, deterministic)
#define JTOL 4e-12f     // skip rotation if d^2 <= na*nb*JTOL
#define NBLK_FP 157     // ceil(NDIR/64)
#define NRND (NSWO*31)  // 217 rounds (16-wave ring, 32 groups of 8)

// ---- workspace layout (element offsets; 4B elements) ----
static const size_t OFF_FEATT = 0;                                // 16384*256 f32
static const size_t OFF_IDX   = OFF_FEATT + (size_t)HWPX*FEAT;    // 4*16384 int
static const size_t OFF_CNT   = OFF_IDX + (size_t)NCLS*HWPX;      // 4 int (+pad)
static const size_t OFF_MIU   = OFF_CNT + 64;                     // 4*256 f32
static const size_t OFF_MIUP  = OFF_MIU + (size_t)NCLS*FEAT;      // 32*4*256 f32 partials
static const size_t OFF_G     = OFF_MIUP + (size_t)32*NCLS*FEAT;  // 4*65536 f32
static const size_t OFF_ETS   = OFF_G + (size_t)NCLS*FEAT*FEAT;   // 4*65536 f32
static const size_t OFF_EVAL  = OFF_ETS + (size_t)NCLS*FEAT*FEAT; // 4*256 f32
static const size_t OFF_LPART = OFF_EVAL + (size_t)NCLS*FEAT;     // 4*160*2 f32 per-block partials
static const size_t OFF_B     = OFF_LPART + (size_t)NCLS*160*2;   // 4*256*BCAP f32
static const size_t OFF_XCH   = OFF_B + (size_t)NCLS*FEAT*BCAP;   // 4*131072 f32 region per class
// per-class sub-layout inside XCH (stride 131072 floats = 512 KB):
//   QIN_w  at w*4096       (w=0..15): 2 slots x 2048 floats (Q arriving at wave w)
//   PIN_w  at 65536+w*4096 (w=1..14): 2 slots x 2048 floats (P arriving at wave w)
//   csqg   at 65536 + 0    (PIN_0 hole, 256 f32: exact column norms)
//   flags  at 65536 + 1024 (PIN_0 hole, ints): dP[16] crP[16] dQ[16] crQ[16] bar
// total unchanged (~39 MB)

#define XCH_STRIDE  ((size_t)131072)
#define XCH_PIN_OFF 65536
#define XCH_FLG_OFF (65536 + 1024)

// native clang vector: first-class register quad, valid for "v" asm constraints
typedef float v4f __attribute__((ext_vector_type(4)));

// 64-lane sum, deterministic fixed order, result uniform.
__device__ __forceinline__ float wsum64(float v){
  int x;
  x = __builtin_amdgcn_update_dpp(0, __float_as_int(v), 0x121, 0xF, 0xF, false); v += __int_as_float(x); // row_ror:1
  x = __builtin_amdgcn_update_dpp(0, __float_as_int(v), 0x122, 0xF, 0xF, false); v += __int_as_float(x); // row_ror:2
  x = __builtin_amdgcn_update_dpp(0, __float_as_int(v), 0x124, 0xF, 0xF, false); v += __int_as_float(x); // row_ror:4
  x = __builtin_amdgcn_update_dpp(0, __float_as_int(v), 0x128, 0xF, 0xF, false); v += __int_as_float(x); // row_ror:8
  float a = __int_as_float(__builtin_amdgcn_readlane(__float_as_int(v), 0));
  float b = __int_as_float(__builtin_amdgcn_readlane(__float_as_int(v), 16));
  float c = __int_as_float(__builtin_amdgcn_readlane(__float_as_int(v), 32));
  float d = __int_as_float(__builtin_amdgcn_readlane(__float_as_int(v), 48));
  return (a + b) + (c + d);
}

// flag ops: AGENT-scope relaxed dword atomics (sc1 path, tiny traffic)
__device__ __forceinline__ void sysst(float* p, float v){
  __hip_atomic_store(p, v, __ATOMIC_RELAXED, __HIP_MEMORY_SCOPE_AGENT);
}
__device__ __forceinline__ float sysld(const float* p){
  return __hip_atomic_load(p, __ATOMIC_RELAXED, __HIP_MEMORY_SCOPE_AGENT);
}
__device__ __forceinline__ void syssti(int* p, int v){
  __hip_atomic_store(p, v, __ATOMIC_RELAXED, __HIP_MEMORY_SCOPE_AGENT);
}
__device__ __forceinline__ int sysldi(const int* p){
  return __hip_atomic_load(p, __ATOMIC_RELAXED, __HIP_MEMORY_SCOPE_AGENT);
}
// whole-wave spin until *f >= val
__device__ __forceinline__ void waitflag(int* f, int val){
  while (sysldi(f) < val) __builtin_amdgcn_s_sleep(1);
  asm volatile("" ::: "memory");
}

// WIDE agent-coherent payload transit: one dwordx4 per lane with sc1 (the exact
// cache-control LLVM uses for agent-scope monotonic access, just 16B wide).
// Payload doesn't need per-dword atomicity -- the flag protocol owns the slots.
// ext_vector_type operands: direct VGPR-quad register class (fixes the
// "indirect register inputs" error that HIP's struct float4 caused).
// NOTE: values from ldwide are valid only after s_waitcnt vmcnt(0) (+sched_barrier).
__device__ __forceinline__ void stwide(float* p, float x, float y, float z, float w){
  v4f v; v.x = x; v.y = y; v.z = z; v.w = w;
  asm volatile("global_store_dwordx4 %0, %1, off sc1" :: "v"(p), "v"(v) : "memory");
}
__device__ __forceinline__ v4f ldwide(const float* p){
  v4f r;
  asm volatile("global_load_dwordx4 %0, %1, off sc1" : "=v"(r) : "v"(p) : "memory");
  return r;
}

// ---------------- transpose feat (256 x 16384) -> featT (16384 x 256) ----------------
__global__ __launch_bounds__(256) void k_transpose(const float* __restrict__ feat, float* __restrict__ ws){
  __shared__ float tile[32][33];
  float* featT = ws + OFF_FEATT;
  int j0 = blockIdx.x*32, f0 = blockIdx.y*32;
  int tx = threadIdx.x, ty = threadIdx.y; // (32, 8)
  #pragma unroll
  for (int r=0;r<4;r++){
    int f = f0 + ty + r*8;
    tile[ty+r*8][tx] = feat[(size_t)f*HWPX + j0 + tx];
  }
  __syncthreads();
  #pragma unroll
  for (int r=0;r<4;r++){
    int j = j0 + ty + r*8;
    featT[(size_t)j*FEAT + f0 + tx] = tile[tx][ty+r*8];
  }
}

// ---------------- build compacted per-class index lists + counts (+ zero jacobi flags) ----------------
__global__ __launch_bounds__(256) void k_index(const int* __restrict__ lab, float* ws){
  __shared__ int sc[256];
  int* idx = (int*)(ws + OFF_IDX);
  int* cnt = (int*)(ws + OFF_CNT);
  int t = threadIdx.x;
  // zero k_jacobi sync flags every launch (graph replay safe; stream-ordered before k_jacobi)
  if (t < 96){
    #pragma unroll
    for (int cc=0; cc<NCLS; cc++){
      int* fb = (int*)(ws + OFF_XCH + (size_t)cc*XCH_STRIDE + XCH_FLG_OFF);
      fb[t] = 0;
    }
  }
  int base = t*64;
  for (int c=1;c<=NCLS;c++){
    __syncthreads();
    int m = 0;
    for (int k=0;k<64;k++) m += (lab[base+k]==c) ? 1 : 0;
    sc[t] = m;
    __syncthreads();
    for (int off=1; off<256; off<<=1){
      int v = (t>=off)? sc[t-off] : 0;
      __syncthreads();
      sc[t] += v;
      __syncthreads();
    }
    int pos = sc[t] - m;
    if (t==255) cnt[c-1] = sc[255];
    int* ic = idx + (size_t)(c-1)*HWPX;
    for (int k=0;k<64;k++){
      if (lab[base+k]==c) ic[pos++] = base+k;
    }
  }
}

// ---------------- per-class feature-sum partials (deterministic, no atomics) ----------------
__global__ __launch_bounds__(256) void k_miu_part(const int* __restrict__ lab, float* ws){
  const float* featT = ws + OFF_FEATT;
  float* part = ws + OFF_MIUP;
  int f = threadIdx.x;
  int b = blockIdx.x;
  int j0 = b*512;
  float a0=0.f,a1=0.f,a2=0.f,a3=0.f;
  for (int j=j0;j<j0+512;j++){
    float v = featT[(size_t)j*FEAT + f];
    int c = lab[j];
    a0 += (c==1)? v : 0.f;
    a1 += (c==2)? v : 0.f;
    a2 += (c==3)? v : 0.f;
    a3 += (c==4)? v : 0.f;
  }
  float* pb = part + (size_t)b*NCLS*FEAT;
  pb[0*FEAT+f] = a0;
  pb[1*FEAT+f] = a1;
  pb[2*FEAT+f] = a2;
  pb[3*FEAT+f] = a3;
}

__global__ __launch_bounds__(1024) void k_miu_fin(float* ws){
  int t = threadIdx.x;            // 0..1023 = c*FEAT+f
  int c = t / FEAT;
  const float* part = ws + OFF_MIUP;
  float s = 0.f;
  for (int b=0;b<32;b++) s += part[(size_t)b*NCLS*FEAT + t];   // fixed order
  int n = ((int*)(ws+OFF_CNT))[c];
  float nf = fmaxf((float)n, 1.f);
  ws[OFF_MIU + t] = s / nf;
}

// ---------------- cov per class (64x64 tiles): G = m2mat/n - miu miu^T + eps I ----------------
__global__ __launch_bounds__(256) void k_cov(float* ws){
  __shared__ float Xa[32][68];
  __shared__ float Xb[32][68];
  const float* featT = ws + OFF_FEATT;
  int c = blockIdx.y;
  const int* idx = (const int*)(ws + OFF_IDX) + (size_t)c*HWPX;
  int n = ((int*)(ws+OFF_CNT))[c];
  float nf = fmaxf((float)n,1.f);
  const float* miu = ws + OFF_MIU + (size_t)c*FEAT;
  float* G = ws + OFF_G + (size_t)c*FEAT*FEAT;
  int fb = (blockIdx.x & 3)*64, gb = (blockIdx.x >> 2)*64;
  int t = threadIdx.x;
  int ti = t & 15, tj = t >> 4;
  float acc[4][4] = {};
  int jr = t >> 3;         // 0..31
  int s8 = (t & 7) * 8;    // 0..56
  int nch = (n + 31)/32;
  for (int ch=0; ch<nch; ch++){
    int jg = ch*32 + jr;
    __syncthreads();
    if (jg < n){
      int jx = idx[jg];
      const float* row = featT + (size_t)jx*FEAT;
      #pragma unroll
      for (int k=0;k<8;k++){ Xa[jr][s8+k] = row[fb+s8+k]; Xb[jr][s8+k] = row[gb+s8+k]; }
    } else {
      #pragma unroll
      for (int k=0;k<8;k++){ Xa[jr][s8+k] = 0.f; Xb[jr][s8+k] = 0.f; }
    }
    __syncthreads();
    for (int jj=0;jj<32;jj++){
      float4 av = *(const float4*)&Xa[jj][ti*4];
      float4 bv = *(const float4*)&Xb[jj][tj*4];
      float aa[4] = {av.x,av.y,av.z,av.w};
      float bb[4] = {bv.x,bv.y,bv.z,bv.w};
      #pragma unroll
      for (int ii=0; ii<4; ii++)
        #pragma unroll
        for (int j2=0; j2<4; j2++)
          acc[ii][j2] += aa[ii]*bb[j2];
    }
  }
  float eps = fminf(fmaxf(1e-5f/nf, 1e-8f), 1e-5f);
  #pragma unroll
  for (int ii=0; ii<4; ii++){
    #pragma unroll
    for (int j2=0; j2<4; j2++){
      int f = fb + ti*4 + ii, g = gb + tj*4 + j2;
      float v = acc[ii][j2]/nf - miu[f]*miu[g] + ((f==g)? eps : 0.f);
      G[(size_t)g*FEAT + f] = v;   // column-major, col g
    }
  }
}

// ---------------- one-sided BLOCK Jacobi, systolic 16-wave ring, 8-col groups ----------------
// Identical ring / tournament / rotation arithmetic / flag protocol to R4 (bit-exact
// expected). ONLY change vs R4: payload transit uses wide non-atomic
// global_{load,store}_dwordx4 with sc1 (agent-coherent) instead of dword atomics --
// 4x fewer VMEM transit instructions, full 64B-sector coverage (no 4x write
// amplification), same visibility guarantees under the vmcnt-then-flag ordering.
// Protocol per round R (publish-before-wait => deadlock-free by induction):
//   1. credit waits  2. data stores (slot (R+1)&1)  3. vmcnt(0)  4. d-flag:=R+1
//   5. tail reg-move 6. wait d>=R+1  7. loads  8. vmcnt(0)+sched_barrier  9. credit:=R+1
__global__ __launch_bounds__(64) void k_jacobi(float* ws){
  int c = blockIdx.y;
  int w = blockIdx.x;                 // ring wave 0..15
  float* G    = ws + OFF_G + (size_t)c*FEAT*FEAT;
  float* XC   = ws + OFF_XCH + (size_t)c*XCH_STRIDE;
  float* QIN  = XC;                   // w*4096 (+ sl*2048)
  float* PIN  = XC + XCH_PIN_OFF;     // w*4096 (+ sl*2048), w=1..14
  float* csqg = XC + XCH_PIN_OFF;     // PIN_0 hole [0..255]
  int*   flg  = (int*)(XC + XCH_FLG_OFF);
  int* dP = flg;       int* crP = flg+16;
  int* dQ = flg+32;    int* crQ = flg+48;
  int* bar = flg+64;
  int lane = threadIdx.x;
  int lane4 = lane*4;

#define FORJ8L(M) M(0) M(1) M(2) M(3) M(4) M(5) M(6) M(7)
#define FORJ8H(M) M(8) M(9) M(10) M(11) M(12) M(13) M(14) M(15)

  // 16 resident columns: 0..7 = P (group pg), 8..15 = Q (group qg)
#define DECL(j) float C##j##x, C##j##y, C##j##z, C##j##w;
  FORJ8L(DECL) FORJ8H(DECL)
#undef DECL
  float n0,n1,n2,n3,n4,n5,n6,n7,n8,n9,n10,n11,n12,n13,n14,n15;

  int pg = (w==0)? 31 : w;        // initial (and final) group ids
  int qg = (w==0)? 0  : 31 - w;

  // initial load (plain cached loads; G flushed at kernel boundary)
#define LDP(j) { float4 v_ = *(const float4*)&G[(size_t)(pg*8+(j))*FEAT + lane4]; \
                 C##j##x=v_.x; C##j##y=v_.y; C##j##z=v_.z; C##j##w=v_.w; }
  FORJ8L(LDP)
#undef LDP
#define LDQ(j) { float4 v_ = *(const float4*)&G[(size_t)(qg*8+((j)-8))*FEAT + lane4]; \
                 C##j##x=v_.x; C##j##y=v_.y; C##j##z=v_.z; C##j##w=v_.w; }
  FORJ8H(LDQ)
#undef LDQ

#define RG(g,ax,ay,az,aw)  ax=C##g##x; ay=C##g##y; az=C##g##z; aw=C##g##w;
#define WRG(g,ax,ay,az,aw) C##g##x=ax; C##g##y=ay; C##g##z=az; C##g##w=aw;
#define NRM(j) n##j = wsum64(C##j##x*C##j##x + C##j##y*C##j##y + C##j##z*C##j##z + C##j##w*C##j##w);

  // Branchless rotation (value-identical to branchy form; verified bit-exact R3).
#define ROTG(ga,gb) { \
    float ax,ay,az,aw,bx,by,bz,bw; \
    RG(ga,ax,ay,az,aw) \
    RG(gb,bx,by,bz,bw) \
    float dp = ax*bx + ay*by + az*bz + aw*bw; \
    float d = wsum64(dp); \
    float na = n##ga, nb = n##gb; \
    bool doit = (d*d > na*nb*JTOL); \
    float tau = (nb - na) * 0.5f * __builtin_amdgcn_rcpf(d); \
    float tt = copysignf(__builtin_amdgcn_rcpf(fabsf(tau) + __builtin_amdgcn_sqrtf(1.f + tau*tau)), tau); \
    float cc = __builtin_amdgcn_rsqf(1.f + tt*tt); \
    float sn = tt*cc; \
    cc = doit ? cc : 1.f; \
    sn = doit ? sn : 0.f; \
    float x_; \
    x_ = ax; ax = cc*x_ - sn*bx; bx = sn*x_ + cc*bx; \
    x_ = ay; ay = cc*x_ - sn*by; by = sn*x_ + cc*by; \
    x_ = az; az = cc*x_ - sn*bz; bz = sn*x_ + cc*bz; \
    x_ = aw; aw = cc*x_ - sn*bw; bw = sn*x_ + cc*bw; \
    float cc2 = cc*cc, sn2 = sn*sn, csd = 2.f*cc*sn*d; \
    n##ga = cc2*na - csd + sn2*nb; \
    n##gb = sn2*na + csd + cc2*nb; \
    WRG(ga,ax,ay,az,aw) \
    WRG(gb,bx,by,bz,bw) \
  }

  // mailbox column store/load (ONE dwordx4 sc1 per lane per column)
#define STC(d_, j) stwide((d_) + ((j)&7)*256 + lane4, C##j##x, C##j##y, C##j##z, C##j##w);
#define LDC(s_, j) { v4f r_ = ldwide((s_) + ((j)&7)*256 + lane4); \
    C##j##x=r_.x; C##j##y=r_.y; C##j##z=r_.z; C##j##w=r_.w; }

  bool hasP = (w>=1 && w<=14);    // receives P mailbox
  float* pubPdst = (w==1)? QIN : PIN + (size_t)(w-1)*4096;   // w>=1
  int*   pubPd   = (w==1)? (dQ+0) : (dP+(w-1));
  int*   pubPcr  = (w==1)? (crQ+0) : (crP+(w-1));

#pragma clang loop unroll(disable)
  for (int R=0; R<NRND; R++){
    // exact column norms (refreshed each round; uniform across lanes)
    NRM(0) NRM(1) NRM(2) NRM(3) NRM(4) NRM(5) NRM(6) NRM(7)
    NRM(8) NRM(9) NRM(10) NRM(11) NRM(12) NRM(13) NRM(14) NRM(15)
    // ---- cross pairs: 8 micro-rounds of 8 disjoint (i, 8+((i+s)&7)) ----
    ROTG(0,8)  ROTG(1,9)  ROTG(2,10) ROTG(3,11) ROTG(4,12) ROTG(5,13) ROTG(6,14) ROTG(7,15)
    ROTG(0,9)  ROTG(1,10) ROTG(2,11) ROTG(3,12) ROTG(4,13) ROTG(5,14) ROTG(6,15) ROTG(7,8)
    ROTG(0,10) ROTG(1,11) ROTG(2,12) ROTG(3,13) ROTG(4,14) ROTG(5,15) ROTG(6,8)  ROTG(7,9)
    ROTG(0,11) ROTG(1,12) ROTG(2,13) ROTG(3,14) ROTG(4,15) ROTG(5,8)  ROTG(6,9)  ROTG(7,10)
    ROTG(0,12) ROTG(1,13) ROTG(2,14) ROTG(3,15) ROTG(4,8)  ROTG(5,9)  ROTG(6,10) ROTG(7,11)
    ROTG(0,13) ROTG(1,14) ROTG(2,15) ROTG(3,8)  ROTG(4,9)  ROTG(5,10) ROTG(6,11) ROTG(7,12)
    ROTG(0,14) ROTG(1,15) ROTG(2,8)  ROTG(3,9)  ROTG(4,10) ROTG(5,11) ROTG(6,12) ROTG(7,13)
    ROTG(0,15) ROTG(1,8)  ROTG(2,9)  ROTG(3,10) ROTG(4,11) ROTG(5,12) ROTG(6,13) ROTG(7,14)
    // ---- intra-group pairs every 4th round (7-round circle per group) ----
    if ((R & 3) == 3){
      ROTG(7,0) ROTG(1,6) ROTG(2,5) ROTG(3,4)  ROTG(15,8)  ROTG(9,14)  ROTG(10,13) ROTG(11,12)
      ROTG(7,1) ROTG(2,0) ROTG(3,6) ROTG(4,5)  ROTG(15,9)  ROTG(10,8)  ROTG(11,14) ROTG(12,13)
      ROTG(7,2) ROTG(3,1) ROTG(4,0) ROTG(5,6)  ROTG(15,10) ROTG(11,9)  ROTG(12,8)  ROTG(13,14)
      ROTG(7,3) ROTG(4,2) ROTG(5,1) ROTG(6,0)  ROTG(15,11) ROTG(12,10) ROTG(13,9)  ROTG(14,8)
      ROTG(7,4) ROTG(5,3) ROTG(6,2) ROTG(0,1)  ROTG(15,12) ROTG(13,11) ROTG(14,10) ROTG(8,9)
      ROTG(7,5) ROTG(6,4) ROTG(0,3) ROTG(1,2)  ROTG(15,13) ROTG(14,12) ROTG(8,11)  ROTG(9,10)
      ROTG(7,6) ROTG(0,5) ROTG(1,4) ROTG(2,3)  ROTG(15,14) ROTG(8,13)  ROTG(9,12)  ROTG(10,11)
    }

    int sl = (R+1) & 1;           // slot parity for data-for-round R+1
    // 1. credit waits (slot free: consumer consumed round R-1)
    if (w >= 1) waitflag(pubPcr, R-1);
    if (w <= 14) waitflag(crQ+(w+1), R-1);
    // 2. publish data (wide sc1 stores)
    if (w >= 1){
      float* db = pubPdst + sl*2048;
      STC(db,0) STC(db,1) STC(db,2) STC(db,3) STC(db,4) STC(db,5) STC(db,6) STC(db,7)
    }
    if (w <= 14){
      float* db = QIN + (size_t)(w+1)*4096 + sl*2048;
      STC(db,8) STC(db,9) STC(db,10) STC(db,11) STC(db,12) STC(db,13) STC(db,14) STC(db,15)
    }
    // 3. data stores complete before flags become visible
    asm volatile("s_waitcnt vmcnt(0)" ::: "memory");
    // 4. publish data flags
    if (w >= 1) syssti(pubPd, R+1);
    if (w <= 14) syssti(dQ+(w+1), R+1);
    // 5. ring tail: newP_15 = own oldQ (register moves; P stores already completed)
    if (w == 15){
      C0x=C8x;  C0y=C8y;  C0z=C8z;  C0w=C8w;
      C1x=C9x;  C1y=C9y;  C1z=C9z;  C1w=C9w;
      C2x=C10x; C2y=C10y; C2z=C10z; C2w=C10w;
      C3x=C11x; C3y=C11y; C3z=C11z; C3w=C11w;
      C4x=C12x; C4y=C12y; C4z=C12z; C4w=C12w;
      C5x=C13x; C5y=C13y; C5z=C13z; C5w=C13w;
      C6x=C14x; C6y=C14y; C6z=C14z; C6w=C14w;
      C7x=C15x; C7y=C15y; C7z=C15z; C7w=C15w;
    }
    // 6. wait for round R+1 inputs
    if (hasP) waitflag(dP+w, R+1);
    waitflag(dQ+w, R+1);
    // 7. receive loads (wide sc1 loads)
    if (hasP){
      const float* sb = PIN + (size_t)w*4096 + sl*2048;
      LDC(sb,0) LDC(sb,1) LDC(sb,2) LDC(sb,3) LDC(sb,4) LDC(sb,5) LDC(sb,6) LDC(sb,7)
    }
    {
      const float* sb = QIN + (size_t)w*4096 + sl*2048;
      LDC(sb,8) LDC(sb,9) LDC(sb,10) LDC(sb,11) LDC(sb,12) LDC(sb,13) LDC(sb,14) LDC(sb,15)
    }
    // 8. loads complete before values are used / credits release the slots
    //    (inline-asm loads are invisible to compiler vmcnt tracking: explicit fence
    //     + sched_barrier so no consumer is hoisted above it -- guide rule #18)
    asm volatile("s_waitcnt vmcnt(0)" ::: "memory");
    __builtin_amdgcn_sched_barrier(0);
    // 9. credits out
    if (hasP) syssti(crP+w, R+1);
    syssti(crQ+w, R+1);
  }

  // ---- extraction: exact norms -> csqg, class barrier, per-wave rank, normalized rows ----
  NRM(0) NRM(1) NRM(2) NRM(3) NRM(4) NRM(5) NRM(6) NRM(7)
  NRM(8) NRM(9) NRM(10) NRM(11) NRM(12) NRM(13) NRM(14) NRM(15)
  int pcol = pg*8, qcol = qg*8;
#define WCSP(j) if (lane == (j)) sysst(&csqg[pcol+(j)], n##j);
#define WCSQ(j) if (lane == (j)) sysst(&csqg[qcol+(j)-8], n##j);
  WCSP(0) WCSP(1) WCSP(2) WCSP(3) WCSP(4) WCSP(5) WCSP(6) WCSP(7)
  WCSQ(8) WCSQ(9) WCSQ(10) WCSQ(11) WCSQ(12) WCSQ(13) WCSQ(14) WCSQ(15)
#undef WCSP
#undef WCSQ
  asm volatile("s_waitcnt vmcnt(0)" ::: "memory");
  if (lane == 0) __hip_atomic_fetch_add(bar, 1, __ATOMIC_RELAXED, __HIP_MEMORY_SCOPE_AGENT);
  while (sysldi(bar) < 16) __builtin_amdgcn_s_sleep(1);
  asm volatile("" ::: "memory");
  // all 256 norms; each lane holds 4
  float q0 = sysld(&csqg[lane4+0]);
  float q1 = sysld(&csqg[lane4+1]);
  float q2 = sysld(&csqg[lane4+2]);
  float q3 = sysld(&csqg[lane4+3]);
  int u0 = lane4, u1 = lane4+1, u2 = lane4+2, u3 = lane4+3;
  float* evals = ws + OFF_EVAL + (size_t)c*FEAT;
  float* Et = ws + OFF_ETS + (size_t)c*FEAT*FEAT;
  // rank(col X, norm nv) = #{u : csq[u] > nv || (== && u < X)}  (same comparator)
#define RANKWR(j, X) { \
    float nv = n##j; \
    float cnt = (((q0>nv)||(q0==nv&&u0<(X)))?1.f:0.f) + (((q1>nv)||(q1==nv&&u1<(X)))?1.f:0.f) \
              + (((q2>nv)||(q2==nv&&u2<(X)))?1.f:0.f) + (((q3>nv)||(q3==nv&&u3<(X)))?1.f:0.f); \
    int rk = (int)wsum64(cnt); \
    if (lane == 0) evals[rk] = sqrtf(nv); \
    float iv = 1.f / sqrtf(nv); \
    float4 v_; v_.x=C##j##x*iv; v_.y=C##j##y*iv; v_.z=C##j##z*iv; v_.w=C##j##w*iv; \
    *(float4*)&Et[(size_t)rk*FEAT + lane4] = v_; \
  }
  RANKWR(0,  pcol+0) RANKWR(1,  pcol+1) RANKWR(2,  pcol+2) RANKWR(3,  pcol+3)
  RANKWR(4,  pcol+4) RANKWR(5,  pcol+5) RANKWR(6,  pcol+6) RANKWR(7,  pcol+7)
  RANKWR(8,  qcol+0) RANKWR(9,  qcol+1) RANKWR(10, qcol+2) RANKWR(11, qcol+3)
  RANKWR(12, qcol+4) RANKWR(13, qcol+5) RANKWR(14, qcol+6) RANKWR(15, qcol+7)
#undef RANKWR
#undef ROTG
#undef NRM
#undef RG
#undef WRG
#undef STC
#undef LDC
#undef FORJ8L
#undef FORJ8H
}

// ---------------- B[c] = EtS (256x256, sorted) @ centered_gathered (256 x n_c) ----------------
__global__ __launch_bounds__(256) void k_bmat(float* ws){
  __shared__ float Ae[256][68];   // [f][k-local]
  __shared__ float Bc[256][68];   // [f][j-local]
  int c = blockIdx.z;
  int n = ((int*)(ws+OFF_CNT))[c];
  int j0 = blockIdx.x*64;
  if (j0 >= n) return;            // block-uniform
  int kb = blockIdx.y*64;
  const float* featT = ws + OFF_FEATT;
  const int* idx = (const int*)(ws + OFF_IDX) + (size_t)c*HWPX;
  const float* miu = ws + OFF_MIU + (size_t)c*FEAT;
  const float* Ets = ws + OFF_ETS + (size_t)c*FEAT*FEAT;
  float* Bg = ws + OFF_B + (size_t)c*FEAT*BCAP;
  int t = threadIdx.x;
  int l4 = t >> 2, sgf = (t & 3)*64;
  // stage Ae
  {
    const float* Erow = Ets + (size_t)(kb+l4)*FEAT + sgf;
    for (int f=0; f<64; f+=4){
      float4 v = *(const float4*)&Erow[f];
      Ae[sgf+f+0][l4] = v.x; Ae[sgf+f+1][l4] = v.y;
      Ae[sgf+f+2][l4] = v.z; Ae[sgf+f+3][l4] = v.w;
    }
  }
  // stage Bc (centered gathered columns)
  {
    int jg = j0 + l4;
    if (jg < n){
      const float* Frow = featT + (size_t)idx[jg]*FEAT + sgf;
      const float* mp = miu + sgf;
      for (int f=0; f<64; f+=4){
        float4 v = *(const float4*)&Frow[f];
        Bc[sgf+f+0][l4] = v.x - mp[f+0];
        Bc[sgf+f+1][l4] = v.y - mp[f+1];
        Bc[sgf+f+2][l4] = v.z - mp[f+2];
        Bc[sgf+f+3][l4] = v.w - mp[f+3];
      }
    } else {
      for (int f=0; f<64; f++) Bc[sgf+f][l4] = 0.f;
    }
  }
  __syncthreads();
  int ti = t & 15, tj = t >> 4;   // ti: k-sub, tj: j-sub
  float acc[4][4] = {};
  for (int f=0; f<FEAT; f+=4){
    #pragma unroll
    for (int ff=0; ff<4; ff++){
      float4 av = *(const float4*)&Ae[f+ff][ti*4];
      float4 bv = *(const float4*)&Bc[f+ff][tj*4];
      float aa[4] = {av.x,av.y,av.z,av.w};
      float bb[4] = {bv.x,bv.y,bv.z,bv.w};
      #pragma unroll
      for (int kk=0;kk<4;kk++)
        #pragma unroll
        for (int jj=0;jj<4;jj++)
          acc[kk][jj] += aa[kk]*bb[jj];
    }
  }
  #pragma unroll
  for (int kk=0; kk<4; kk++){
    float4 o; o.x=acc[kk][0]; o.y=acc[kk][1]; o.z=acc[kk][2]; o.w=acc[kk][3];
    *(float4*)&Bg[(size_t)(kb + ti*4 + kk)*BCAP + j0 + tj*4] = o;
  }
}

// ---------------- fp GEMM (pm @ B) with fused m2/m4 + per-block loss partials ----------------
__global__ __launch_bounds__(256) void k_fp(const float* __restrict__ pm, float* ws){
  __shared__ float As[256][68];   // [k][i-local]  (pm tile, transposed)
  __shared__ float Bs[256][68];   // [k][j-local]
  __shared__ float ev[256];
  __shared__ float red[64][17];
  __shared__ float m2s[64];
  __shared__ float m4s[64];
  int c = blockIdx.y;
  int i0 = blockIdx.x*64;
  int n = ((int*)(ws+OFF_CNT))[c];
  float nf = fmaxf((float)n, 1.f);
  const float* evals = ws + OFF_EVAL + (size_t)c*FEAT;
  const float* Bg = ws + OFF_B + (size_t)c*FEAT*BCAP;
  int t = threadIdx.x;
  int l4 = t >> 2;
  // stage As
  {
    int sgf = (t & 3)*64;
    int gi = i0 + l4;
    if (gi < NDIR){
      const float* row = pm + (size_t)gi*FEAT + sgf;
      for (int f=0; f<64; f+=4){
        float4 v = *(const float4*)&row[f];
        As[sgf+f+0][l4] = v.x; As[sgf+f+1][l4] = v.y;
        As[sgf+f+2][l4] = v.z; As[sgf+f+3][l4] = v.w;
      }
    } else {
      for (int f=0; f<64; f++) As[sgf+f][l4] = 0.f;
    }
  }
  if (t < 256) ev[t] = evals[t];
  int ti = t & 15, tj = t >> 4;
  float s2[4] = {0.f,0.f,0.f,0.f};
  float s4[4] = {0.f,0.f,0.f,0.f};
  int nch = (n + 63)/64;
  int sgj = (t & 3)*16;
  for (int ch=0; ch<nch; ch++){
    int j0 = ch*64;
    __syncthreads();
    for (int g=0; g<4; g++){
      int r = l4 + 64*g;
      const float* Brow = Bg + (size_t)r*BCAP + j0 + sgj;
      #pragma unroll
      for (int e=0; e<16; e+=4){
        int j = j0 + sgj + e;
        float4 v;
        if (j + 3 < n) v = *(const float4*)&Brow[e];
        else {
          v.x = (j+0<n)? Brow[e+0] : 0.f;
          v.y = (j+1<n)? Brow[e+1] : 0.f;
          v.z = (j+2<n)? Brow[e+2] : 0.f;
          v.w = (j+3<n)? Brow[e+3] : 0.f;
        }
        *(float4*)&Bs[r][sgj+e] = v;
      }
    }
    __syncthreads();
    float acc[4][4] = {};
    for (int k=0; k<FEAT; k+=4){
      #pragma unroll
      for (int kk=0; kk<4; kk++){
        float4 av = *(const float4*)&As[k+kk][ti*4];
        float4 bv = *(const float4*)&Bs[k+kk][tj*4];
        float aa[4] = {av.x,av.y,av.z,av.w};
        float bb[4] = {bv.x,bv.y,bv.z,bv.w};
        #pragma unroll
        for (int ii=0;ii<4;ii++)
          #pragma unroll
          for (int jj=0;jj<4;jj++)
            acc[ii][jj] += aa[ii]*bb[jj];
      }
    }
    #pragma unroll
    for (int ii=0;ii<4;ii++){
      #pragma unroll
      for (int jj=0;jj<4;jj++){
        float v = acc[ii][jj];
        float v2 = v*v;
        s2[ii] += v2;
        s4[ii] += v2*v2;
      }
    }
  }
  __syncthreads();
  #pragma unroll
  for (int ii=0;ii<4;ii++) red[ti*4+ii][tj] = s2[ii];
  __syncthreads();
  if (t < 64){
    float s = 0.f;
    for (int u=0;u<16;u++) s += red[t][u];
    m2s[t] = s;
  }
  __syncthreads();
  #pragma unroll
  for (int ii=0;ii<4;ii++) red[ti*4+ii][tj] = s4[ii];
  __syncthreads();
  if (t < 64){
    float s = 0.f;
    for (int u=0;u<16;u++) s += red[t][u];
    m4s[t] = s;
  }
  __syncthreads();
  if (t < 64){
    float stds = 0.f;
    for (int k=0;k<FEAT;k++){
      float a = As[k][t];
      stds += a*a*ev[k];
    }
    int i = i0 + t;
    float l2 = 0.f, lk = 0.f;
    if (i < NDIR){
      float m2 = m2s[t]/(nf*stds);
      float m4 = m4s[t]/(nf*stds*stds);
      float d2 = m2 - 1.f;
      l2 = d2*d2;
      float dk = m4 - 3.f*m2*m2;
      lk = dk*dk;
    }
    #pragma unroll
    for (int o=1;o<64;o<<=1){
      l2 += __shfl_xor(l2, o);
      lk += __shfl_xor(lk, o);
    }
    if (t == 0){
      float* lp = ws + OFF_LPART + ((size_t)c*160 + blockIdx.x)*2;
      lp[0] = l2;
      lp[1] = lk;
    }
  }
}

// ---------------- final scalar (deterministic fixed-order reduction) ----------------
__global__ __launch_bounds__(64) void k_final(float* ws, float* out){
  int t = threadIdx.x;   // one wave
  const int* cnt = (const int*)(ws + OFF_CNT);
  const float* lp = ws + OFF_LPART;
  float tot = 0.f, an = 0.f;
  for (int c=0;c<NCLS;c++){
    float s2 = 0.f, sk = 0.f;
    for (int b=t; b<NBLK_FP; b+=64){
      s2 += lp[((size_t)c*160 + b)*2 + 0];
      sk += lp[((size_t)c*160 + b)*2 + 1];
    }
    #pragma unroll
    for (int o=1;o<64;o<<=1){
      s2 += __shfl_xor(s2, o);
      sk += __shfl_xor(sk, o);
    }
    if (cnt[c] > 0){
      tot += s2/(float)NDIR + sk/(float)NDIR;
      an += 1.f;
    }
  }
  if (t == 0) out[0] = tot / fmaxf(an, 1.f);
}

extern "C" void kernel_launch(void* const* d_in, const int* in_sizes, int n_in,
                              void* d_out, int out_size, void* d_ws, size_t ws_size,
                              hipStream_t stream) {
  const float* feat = (const float*)d_in[0];
  const int*   lab  = (const int*)d_in[1];
  const float* pm   = (const float*)d_in[2];
  float* out = (float*)d_out;
  float* ws  = (float*)d_ws;

  hipLaunchKernelGGL(k_transpose, dim3(HWPX/32, FEAT/32), dim3(32,8), 0, stream, feat, ws);
  hipLaunchKernelGGL(k_index,     dim3(1),            dim3(256),     0, stream, lab, ws);
  hipLaunchKernelGGL(k_miu_part,  dim3(32),           dim3(256),     0, stream, lab, ws);
  hipLaunchKernelGGL(k_miu_fin,   dim3(1),            dim3(1024),    0, stream, ws);
  hipLaunchKernelGGL(k_cov,       dim3(16, NCLS),     dim3(256),     0, stream, ws);
  hipLaunchKernelGGL(k_jacobi,    dim3(16, NCLS),     dim3(64),      0, stream, ws);
  hipLaunchKernelGGL(k_bmat,      dim3(BCAP/64, 4, NCLS), dim3(256), 0, stream, ws);
  hipLaunchKernelGGL(k_fp,        dim3(NBLK_FP, NCLS), dim3(256),    0, stream, pm, ws);
  hipLaunchKernelGGL(k_final,     dim3(1),            dim3(64),      0, stream, ws, out);
}